// Round 1
// baseline (4207.326 us; speedup 1.0000x reference)
//
#include <hip/hip_runtime.h>

// ---------------------------------------------------------------------------
// LRA_GNN: random-walk diffusion -> 8-head GAT -> 12-layer residual GCN -> FC
// Strategy: build CSR (pull-based, atomic-free aggregation), wave-per-node
// gather kernels, fused GEMM epilogues (dis-scale, bias, residual, relu).
// ---------------------------------------------------------------------------

__device__ __forceinline__ float lrelu(float v) { return v > 0.f ? v : 0.2f * v; }

// ----------------------------- CSR construction ----------------------------

__global__ void k_count(const int* __restrict__ ei, int E,
                        int* __restrict__ degA, int* __restrict__ degB) {
  int e = blockIdx.x * blockDim.x + threadIdx.x;
  if (e < E) {
    atomicAdd(&degA[ei[e]], 1);       // keyed by edge_index[0] (row)
    atomicAdd(&degB[ei[E + e]], 1);   // keyed by edge_index[1] (dst)
  }
}

__global__ void k_scan1(const int* __restrict__ in, int* __restrict__ tmp,
                        int* __restrict__ bsum, int n) {
  __shared__ int s[256];
  int i = blockIdx.x * 256 + threadIdx.x;
  int v = (i < n) ? in[i] : 0;
  s[threadIdx.x] = v;
  __syncthreads();
  for (int d = 1; d < 256; d <<= 1) {
    int t = (threadIdx.x >= d) ? s[threadIdx.x - d] : 0;
    __syncthreads();
    s[threadIdx.x] += t;
    __syncthreads();
  }
  if (i < n) tmp[i] = s[threadIdx.x];
  if (threadIdx.x == 255) bsum[blockIdx.x] = s[255];
}

__global__ void k_scan2(int* __restrict__ bsum, int nb) {
  __shared__ int s[1024];
  int t = threadIdx.x;
  s[t] = (t < nb) ? bsum[t] : 0;
  __syncthreads();
  for (int d = 1; d < 1024; d <<= 1) {
    int v = (t >= d) ? s[t - d] : 0;
    __syncthreads();
    s[t] += v;
    __syncthreads();
  }
  if (t < nb) bsum[t] = s[t];
}

__global__ void k_scan3(const int* __restrict__ tmp, const int* __restrict__ bsum,
                        int* __restrict__ off, int n) {
  int i = blockIdx.x * 256 + threadIdx.x;
  if (i < n) {
    int add = (blockIdx.x > 0) ? bsum[blockIdx.x - 1] : 0;
    off[i + 1] = tmp[i] + add;
    if (i == 0) off[0] = 0;
  }
}

__global__ void k_prep(const int* __restrict__ offA, const int* __restrict__ offB,
                       int* __restrict__ curA, int* __restrict__ curB,
                       float* __restrict__ dis, int n) {
  int i = blockIdx.x * blockDim.x + threadIdx.x;
  if (i < n) {
    curA[i] = offA[i];
    curB[i] = offB[i];
    // deg under d2 includes the self loop -> always >= 1
    dis[i] = rsqrtf((float)(offB[i + 1] - offB[i] + 1));
  }
}

__global__ void k_fill(const int* __restrict__ ei, int E,
                       int* __restrict__ curA, int* __restrict__ curB,
                       int* __restrict__ idxA, int* __restrict__ idxB) {
  int e = blockIdx.x * blockDim.x + threadIdx.x;
  if (e < E) {
    int s = ei[e], d = ei[E + e];
    int pa = atomicAdd(&curA[s], 1);
    idxA[pa] = d;                      // CSR_A: node=row, neighbor=col
    int pb = atomicAdd(&curB[d], 1);
    idxB[pb] = s;                      // CSR_B: node=dst, neighbor=src
  }
}

// --------------------------------- GEMMs -----------------------------------

// H[row, c] = sum_k X[row,k] * W[k,c]   (optionally * dis[row])
template <bool SCALE>
__global__ __launch_bounds__(256) void k_gemm64(
    const float* __restrict__ X, const float* __restrict__ W,
    const float* __restrict__ dis, float* __restrict__ H, int n) {
  __shared__ float Wl[4096];
  for (int i = threadIdx.x; i < 4096; i += 256) Wl[i] = W[i];
  __syncthreads();
  int lane = threadIdx.x & 63;
  int wid = threadIdx.x >> 6;
  for (int row = blockIdx.x * 4 + wid; row < n; row += gridDim.x * 4) {
    float xv = X[row * 64 + lane];
    float acc = 0.f;
#pragma unroll
    for (int k = 0; k < 64; ++k)
      acc = fmaf(__shfl(xv, k, 64), Wl[k * 64 + lane], acc);
    if (SCALE) acc *= dis[row];
    H[row * 64 + lane] = acc;
  }
}

// GAT projection: Hg[n, h*8+dd] = sum_f x[n,f]*W[h,f,dd]; al[n,0..7]=h.a_src,
// al[n,8..15]=h.a_dst
__global__ __launch_bounds__(256) void k_gat_gemm(
    const float* __restrict__ X, const float* __restrict__ W,
    const float* __restrict__ asrc, const float* __restrict__ adst,
    float* __restrict__ Hg, float* __restrict__ al, int n) {
  __shared__ float Wl[4096];
  for (int i = threadIdx.x; i < 4096; i += 256) {
    int k = i >> 6, c = i & 63;
    Wl[i] = W[(c >> 3) * 512 + k * 8 + (c & 7)];  // [H][IN_C][D] -> [k][c]
  }
  __syncthreads();
  int lane = threadIdx.x & 63;
  int wid = threadIdx.x >> 6;
  float as_c = asrc[lane], ad_c = adst[lane];  // flat [8][8] == lane
  for (int row = blockIdx.x * 4 + wid; row < n; row += gridDim.x * 4) {
    float xv = X[row * 64 + lane];
    float acc = 0.f;
#pragma unroll
    for (int k = 0; k < 64; ++k)
      acc = fmaf(__shfl(xv, k, 64), Wl[k * 64 + lane], acc);
    Hg[row * 64 + lane] = acc;
    float ps = acc * as_c, pd = acc * ad_c;
    ps += __shfl_xor(ps, 1, 64); ps += __shfl_xor(ps, 2, 64); ps += __shfl_xor(ps, 4, 64);
    pd += __shfl_xor(pd, 1, 64); pd += __shfl_xor(pd, 2, 64); pd += __shfl_xor(pd, 4, 64);
    int sub = lane & 7, h = lane >> 3;
    if (sub == 0) al[row * 16 + h] = ps;
    if (sub == 1) al[row * 16 + 8 + h] = pd;
  }
}

// ------------------------------ aggregations -------------------------------

enum { MODE_RW = 0, MODE_G0 = 1, MODE_GR = 2, MODE_GD = 3 };

// One wave per destination node; lane = feature channel.
template <int MODE>
__global__ __launch_bounds__(256) void k_agg(
    const int* __restrict__ off, const int* __restrict__ idx,
    const float* __restrict__ H, const float* __restrict__ dis,
    const float* __restrict__ bias, float* __restrict__ R,
    float* __restrict__ Xo, int n) {
  int lane = threadIdx.x & 63;
  int d = blockIdx.x * 4 + (threadIdx.x >> 6);
  if (d >= n) return;
  int beg = off[d], end = off[d + 1];
  float acc = 0.f;
  for (int base = beg; base < end; base += 64) {
    int cnt = end - base;
    if (cnt > 64) cnt = 64;
    int sidx = (lane < cnt) ? idx[base + lane] : 0;
    int j = 0;
    for (; j + 4 <= cnt; j += 4) {
      int s0 = __shfl(sidx, j, 64), s1 = __shfl(sidx, j + 1, 64);
      int s2 = __shfl(sidx, j + 2, 64), s3 = __shfl(sidx, j + 3, 64);
      float v0 = H[s0 * 64 + lane], v1 = H[s1 * 64 + lane];
      float v2 = H[s2 * 64 + lane], v3 = H[s3 * 64 + lane];
      acc += v0; acc += v1; acc += v2; acc += v3;
    }
    for (; j < cnt; ++j) {
      int s = __shfl(sidx, j, 64);
      acc += H[s * 64 + lane];
    }
  }
  int o = d * 64 + lane;
  if (MODE == MODE_RW) {
    Xo[o] = acc;
  } else {
    // H rows are pre-scaled by dis[s]; self term: dis[d]^2*(xW)[d] = dis[d]*H[d]
    float val = dis[d] * (acc + H[o]) + bias[lane];
    if (MODE == MODE_GR) { val += R[o]; R[o] = val; }
    if (MODE == MODE_GD) Xo[o] = Xo[o] + val;
    else Xo[o] = fmaxf(val, 0.f);
  }
}

// GAT softmax aggregation (2-pass: max, then sum), self loop included.
__global__ __launch_bounds__(256) void k_gat_agg(
    const int* __restrict__ off, const int* __restrict__ idx,
    const float* __restrict__ Hg, const float* __restrict__ al,
    const float* __restrict__ bias, float* __restrict__ Xo,
    float* __restrict__ R, int n) {
  int lane = threadIdx.x & 63;
  int d = blockIdx.x * 4 + (threadIdx.x >> 6);
  if (d >= n) return;
  int h = lane >> 3;
  float ald_d = al[d * 16 + 8 + h];
  float eself = lrelu(al[d * 16 + h] + ald_d);
  int beg = off[d], end = off[d + 1];
  float m = eself;
  for (int base = beg; base < end; base += 64) {
    int cnt = end - base;
    if (cnt > 64) cnt = 64;
    int sidx = (lane < cnt) ? idx[base + lane] : 0;
    for (int j = 0; j < cnt; ++j) {
      int s = __shfl(sidx, j, 64);
      m = fmaxf(m, lrelu(al[s * 16 + h] + ald_d));
    }
  }
  float denom = __expf(eself - m);
  float acc = denom * Hg[d * 64 + lane];
  for (int base = beg; base < end; base += 64) {
    int cnt = end - base;
    if (cnt > 64) cnt = 64;
    int sidx = (lane < cnt) ? idx[base + lane] : 0;
    for (int j = 0; j < cnt; ++j) {
      int s = __shfl(sidx, j, 64);
      float p = __expf(lrelu(al[s * 16 + h] + ald_d) - m);
      denom += p;
      acc = fmaf(p, Hg[s * 64 + lane], acc);
    }
  }
  float val = acc / denom + bias[lane];
  int o = d * 64 + lane;
  Xo[o] = val;
  R[o] = val;  // initial_residual = GAT output
}

// ------------------------------- final linear ------------------------------

__global__ __launch_bounds__(256) void k_fc(
    const float* __restrict__ X, const float* __restrict__ W,
    const float* __restrict__ b, float* __restrict__ out, int n) {
  __shared__ float Wl[640];
  __shared__ float bl[10];
  for (int i = threadIdx.x; i < 640; i += 256) Wl[i] = W[i];
  if (threadIdx.x < 10) bl[threadIdx.x] = b[threadIdx.x];
  __syncthreads();
  int r = blockIdx.x * blockDim.x + threadIdx.x;
  if (r >= n) return;
  float acc[10];
#pragma unroll
  for (int c = 0; c < 10; ++c) acc[c] = bl[c];
#pragma unroll
  for (int k = 0; k < 64; ++k) {
    float xv = X[r * 64 + k];
#pragma unroll
    for (int c = 0; c < 10; ++c) acc[c] = fmaf(xv, Wl[k * 10 + c], acc[c]);
  }
#pragma unroll
  for (int c = 0; c < 10; ++c) out[r * 10 + c] = acc[c];
}

// --------------------------------- launch ----------------------------------

extern "C" void kernel_launch(void* const* d_in, const int* in_sizes, int n_in,
                              void* d_out, int out_size, void* d_ws, size_t ws_size,
                              hipStream_t stream) {
  const float* x_in  = (const float*)d_in[0];
  const int*   ei    = (const int*)d_in[1];
  const float* gatW  = (const float*)d_in[2];
  const float* gatAs = (const float*)d_in[3];
  const float* gatAd = (const float*)d_in[4];
  const float* gatB  = (const float*)d_in[5];
  const float* gcnW  = (const float*)d_in[6];
  const float* gcnB  = (const float*)d_in[7];
  const float* fcW   = (const float*)d_in[8];
  const float* fcB   = (const float*)d_in[9];
  float* out = (float*)d_out;

  const int N = in_sizes[0] / 64;
  const int E = in_sizes[1] / 2;

  char* ws = (char*)d_ws;
  size_t o = 0;
  auto alloc = [&](size_t bytes) -> char* {
    char* p = ws + o;
    o = (o + bytes + 255) & ~(size_t)255;
    return p;
  };
  int* offA   = (int*)alloc((size_t)(N + 1) * 4);
  int* offB   = (int*)alloc((size_t)(N + 1) * 4);
  int* curA   = (int*)alloc((size_t)N * 4);   // doubles as degA
  int* curB   = (int*)alloc((size_t)N * 4);   // doubles as degB
  int* tmp    = (int*)alloc((size_t)N * 4);
  int* bscan  = (int*)alloc(1024 * 4);
  float* dis  = (float*)alloc((size_t)N * 4);
  int* idxA   = (int*)alloc((size_t)E * 4);
  int* idxB   = (int*)alloc((size_t)E * 4);
  float* al   = (float*)alloc((size_t)N * 16 * 4);
  float* X    = (float*)alloc((size_t)N * 64 * 4);
  float* H    = (float*)alloc((size_t)N * 64 * 4);
  float* R    = (float*)alloc((size_t)N * 64 * 4);

  int nbN = (N + 255) / 256;
  int nbE = (E + 255) / 256;
  int nbAgg = (N + 3) / 4;

  // ---- CSR build ----
  hipMemsetAsync(curA, 0, (size_t)N * 4, stream);
  hipMemsetAsync(curB, 0, (size_t)N * 4, stream);
  k_count<<<nbE, 256, 0, stream>>>(ei, E, curA, curB);
  k_scan1<<<nbN, 256, 0, stream>>>(curA, tmp, bscan, N);
  k_scan2<<<1, 1024, 0, stream>>>(bscan, nbN);
  k_scan3<<<nbN, 256, 0, stream>>>(tmp, bscan, offA, N);
  k_scan1<<<nbN, 256, 0, stream>>>(curB, tmp, bscan, N);
  k_scan2<<<1, 1024, 0, stream>>>(bscan, nbN);
  k_scan3<<<nbN, 256, 0, stream>>>(tmp, bscan, offB, N);
  k_prep<<<nbN, 256, 0, stream>>>(offA, offB, curA, curB, dis, N);
  k_fill<<<nbE, 256, 0, stream>>>(ei, E, curA, curB, idxA, idxB);

  // ---- random walk: 5 steps, ping-pong ----
  k_agg<MODE_RW><<<nbAgg, 256, 0, stream>>>(offA, idxA, x_in, nullptr, nullptr, nullptr, X, N);
  k_agg<MODE_RW><<<nbAgg, 256, 0, stream>>>(offA, idxA, X, nullptr, nullptr, nullptr, H, N);
  k_agg<MODE_RW><<<nbAgg, 256, 0, stream>>>(offA, idxA, H, nullptr, nullptr, nullptr, X, N);
  k_agg<MODE_RW><<<nbAgg, 256, 0, stream>>>(offA, idxA, X, nullptr, nullptr, nullptr, H, N);
  k_agg<MODE_RW><<<nbAgg, 256, 0, stream>>>(offA, idxA, H, nullptr, nullptr, nullptr, X, N);

  // ---- GAT ----
  k_gat_gemm<<<2048, 256, 0, stream>>>(X, gatW, gatAs, gatAd, H, al, N);
  k_gat_agg<<<nbAgg, 256, 0, stream>>>(offB, idxB, H, al, gatB, X, R, N);

  // ---- residual GCN ----
  for (int i = 0; i < 12; ++i) {
    k_gemm64<true><<<2048, 256, 0, stream>>>(X, gcnW + i * 4096, dis, H, N);
    if (i == 0)
      k_agg<MODE_G0><<<nbAgg, 256, 0, stream>>>(offB, idxB, H, dis, gcnB + i * 64, nullptr, X, N);
    else
      k_agg<MODE_GR><<<nbAgg, 256, 0, stream>>>(offB, idxB, H, dis, gcnB + i * 64, R, X, N);
    if (i < 11) {
      int j = (i == 0) ? 11 : i - 1;
      k_gemm64<true><<<2048, 256, 0, stream>>>(X, gcnW + j * 4096, dis, H, N);
      k_agg<MODE_GD><<<nbAgg, 256, 0, stream>>>(offB, idxB, H, dis, gcnB + j * 64, nullptr, X, N);
    }
  }

  // ---- final linear ----
  k_fc<<<nbN, 256, 0, stream>>>(X, fcW, fcB, out, N);
}

// Round 2
// 3175.115 us; speedup vs baseline: 1.3251x; 1.3251x over previous
//
#include <hip/hip_runtime.h>

// ---------------------------------------------------------------------------
// LRA_GNN: random-walk diffusion -> 8-head GAT -> 12-layer residual GCN -> FC
// CSR pull-based aggregation. Round 2: float4 aggregation (4 neighbor rows
// per wave-iter) and shfl-free GEMM (lane=row, acc[64], scalar-uniform W).
// ---------------------------------------------------------------------------

__device__ __forceinline__ float lrelu(float v) { return v > 0.f ? v : 0.2f * v; }

// ----------------------------- CSR construction ----------------------------

__global__ void k_count(const int* __restrict__ ei, int E,
                        int* __restrict__ degA, int* __restrict__ degB) {
  int e = blockIdx.x * blockDim.x + threadIdx.x;
  if (e < E) {
    atomicAdd(&degA[ei[e]], 1);       // keyed by edge_index[0] (row)
    atomicAdd(&degB[ei[E + e]], 1);   // keyed by edge_index[1] (dst)
  }
}

__global__ void k_scan1(const int* __restrict__ in, int* __restrict__ tmp,
                        int* __restrict__ bsum, int n) {
  __shared__ int s[256];
  int i = blockIdx.x * 256 + threadIdx.x;
  int v = (i < n) ? in[i] : 0;
  s[threadIdx.x] = v;
  __syncthreads();
  for (int d = 1; d < 256; d <<= 1) {
    int t = (threadIdx.x >= d) ? s[threadIdx.x - d] : 0;
    __syncthreads();
    s[threadIdx.x] += t;
    __syncthreads();
  }
  if (i < n) tmp[i] = s[threadIdx.x];
  if (threadIdx.x == 255) bsum[blockIdx.x] = s[255];
}

__global__ void k_scan2(int* __restrict__ bsum, int nb) {
  __shared__ int s[1024];
  int t = threadIdx.x;
  s[t] = (t < nb) ? bsum[t] : 0;
  __syncthreads();
  for (int d = 1; d < 1024; d <<= 1) {
    int v = (t >= d) ? s[t - d] : 0;
    __syncthreads();
    s[t] += v;
    __syncthreads();
  }
  if (t < nb) bsum[t] = s[t];
}

__global__ void k_scan3(const int* __restrict__ tmp, const int* __restrict__ bsum,
                        int* __restrict__ off, int n) {
  int i = blockIdx.x * 256 + threadIdx.x;
  if (i < n) {
    int add = (blockIdx.x > 0) ? bsum[blockIdx.x - 1] : 0;
    off[i + 1] = tmp[i] + add;
    if (i == 0) off[0] = 0;
  }
}

__global__ void k_prep(const int* __restrict__ offA, const int* __restrict__ offB,
                       int* __restrict__ curA, int* __restrict__ curB,
                       float* __restrict__ dis, int n) {
  int i = blockIdx.x * blockDim.x + threadIdx.x;
  if (i < n) {
    curA[i] = offA[i];
    curB[i] = offB[i];
    dis[i] = rsqrtf((float)(offB[i + 1] - offB[i] + 1));
  }
}

__global__ void k_fill(const int* __restrict__ ei, int E,
                       int* __restrict__ curA, int* __restrict__ curB,
                       int* __restrict__ idxA, int* __restrict__ idxB) {
  int e = blockIdx.x * blockDim.x + threadIdx.x;
  if (e < E) {
    int s = ei[e], d = ei[E + e];
    int pa = atomicAdd(&curA[s], 1);
    idxA[pa] = d;                      // CSR_A: node=row, neighbor=col
    int pb = atomicAdd(&curB[d], 1);
    idxB[pb] = s;                      // CSR_B: node=dst, neighbor=src
  }
}

// --------------------------------- GEMMs -----------------------------------

// H[row, c] = (sum_k X[row,k] * W[k,c]) * (SCALE ? dis[row] : 1)
// lane = row; acc[64] in VGPRs; W accessed wave-uniformly (scalar loads).
template <bool SCALE>
__global__ __launch_bounds__(256) void k_gemm64(
    const float* __restrict__ X, const float* __restrict__ W,
    const float* __restrict__ dis, float* __restrict__ H, int n) {
  int lane = threadIdx.x & 63;
  int wid = threadIdx.x >> 6;
  int row = (blockIdx.x * 4 + wid) * 64 + lane;
  bool valid = row < n;
  const float4* X4 = (const float4*)X;
  float acc[64];
#pragma unroll
  for (int c = 0; c < 64; ++c) acc[c] = 0.f;
  for (int k4 = 0; k4 < 16; ++k4) {
    float4 xv = valid ? X4[(size_t)row * 16 + k4] : float4{0.f, 0.f, 0.f, 0.f};
    float xs[4] = {xv.x, xv.y, xv.z, xv.w};
#pragma unroll
    for (int kk = 0; kk < 4; ++kk) {
      int k = k4 * 4 + kk;
      float xk = xs[kk];
#pragma unroll
      for (int c = 0; c < 64; ++c)
        acc[c] = fmaf(xk, W[k * 64 + c], acc[c]);
    }
  }
  if (!valid) return;
  float sc = SCALE ? dis[row] : 1.f;
  float4* H4 = (float4*)H;
#pragma unroll
  for (int c4 = 0; c4 < 16; ++c4) {
    float4 v = {acc[c4 * 4] * sc, acc[c4 * 4 + 1] * sc,
                acc[c4 * 4 + 2] * sc, acc[c4 * 4 + 3] * sc};
    H4[(size_t)row * 16 + c4] = v;
  }
}

// GAT projection (kept from round 1 — single dispatch, not hot).
__global__ __launch_bounds__(256) void k_gat_gemm(
    const float* __restrict__ X, const float* __restrict__ W,
    const float* __restrict__ asrc, const float* __restrict__ adst,
    float* __restrict__ Hg, float* __restrict__ al, int n) {
  __shared__ float Wl[4096];
  for (int i = threadIdx.x; i < 4096; i += 256) {
    int k = i >> 6, c = i & 63;
    Wl[i] = W[(c >> 3) * 512 + k * 8 + (c & 7)];  // [H][IN_C][D] -> [k][c]
  }
  __syncthreads();
  int lane = threadIdx.x & 63;
  int wid = threadIdx.x >> 6;
  float as_c = asrc[lane], ad_c = adst[lane];  // flat [8][8] == lane
  for (int row = blockIdx.x * 4 + wid; row < n; row += gridDim.x * 4) {
    float xv = X[row * 64 + lane];
    float acc = 0.f;
#pragma unroll
    for (int k = 0; k < 64; ++k)
      acc = fmaf(__shfl(xv, k, 64), Wl[k * 64 + lane], acc);
    Hg[row * 64 + lane] = acc;
    float ps = acc * as_c, pd = acc * ad_c;
    ps += __shfl_xor(ps, 1, 64); ps += __shfl_xor(ps, 2, 64); ps += __shfl_xor(ps, 4, 64);
    pd += __shfl_xor(pd, 1, 64); pd += __shfl_xor(pd, 2, 64); pd += __shfl_xor(pd, 4, 64);
    int sub = lane & 7, h = lane >> 3;
    if (sub == 0) al[row * 16 + h] = ps;
    if (sub == 1) al[row * 16 + 8 + h] = pd;
  }
}

// ------------------------------ aggregations -------------------------------

enum { MODE_RW = 0, MODE_G0 = 1, MODE_GR = 2, MODE_GD = 3 };

// One wave per destination node. lane = (rowgroup rg 0..3, colgroup cg 0..15);
// each iteration gathers 4 neighbor rows as float4 (1KB/inst in flight).
template <int MODE>
__global__ __launch_bounds__(256) void k_agg(
    const int* __restrict__ off, const int* __restrict__ idx,
    const float* __restrict__ H, const float* __restrict__ dis,
    const float* __restrict__ bias, float* __restrict__ R,
    float* __restrict__ Xo, int n) {
  int lane = threadIdx.x & 63;
  int d = blockIdx.x * 4 + (threadIdx.x >> 6);
  if (d >= n) return;
  int rg = lane >> 4, cg = lane & 15;
  int beg = off[d], end = off[d + 1];
  const float4* H4 = (const float4*)H;
  float4 acc = {0.f, 0.f, 0.f, 0.f};
  for (int base = beg; base < end; base += 64) {
    int cnt = end - base;
    if (cnt > 64) cnt = 64;
    int sidx = (lane < cnt) ? idx[base + lane] : -1;
    int nIter = (cnt + 3) >> 2;
    for (int j = 0; j < nIter; ++j) {
      int s = __shfl(sidx, j * 4 + rg, 64);
      if (s >= 0) {
        float4 v = H4[(size_t)s * 16 + cg];
        acc.x += v.x; acc.y += v.y; acc.z += v.z; acc.w += v.w;
      }
    }
  }
  // reduce across rowgroups (lanes cg, cg+16, cg+32, cg+48)
#pragma unroll
  for (int m = 16; m < 64; m <<= 1) {
    acc.x += __shfl_xor(acc.x, m, 64);
    acc.y += __shfl_xor(acc.y, m, 64);
    acc.z += __shfl_xor(acc.z, m, 64);
    acc.w += __shfl_xor(acc.w, m, 64);
  }
  if (rg != 0) return;
  size_t o4 = (size_t)d * 16 + cg;
  float4* Xo4 = (float4*)Xo;
  if (MODE == MODE_RW) {
    Xo4[o4] = acc;
    return;
  }
  // H rows pre-scaled by dis[s]; self term: dis[d]^2*(xW)[d] = dis[d]*H[d]
  float dd = dis[d];
  float4 hs = H4[o4];
  float4 b4 = ((const float4*)bias)[cg];
  float4 val = {dd * (acc.x + hs.x) + b4.x, dd * (acc.y + hs.y) + b4.y,
                dd * (acc.z + hs.z) + b4.z, dd * (acc.w + hs.w) + b4.w};
  if (MODE == MODE_GR) {
    float4* R4 = (float4*)R;
    float4 r = R4[o4];
    val.x += r.x; val.y += r.y; val.z += r.z; val.w += r.w;
    R4[o4] = val;
    Xo4[o4] = {fmaxf(val.x, 0.f), fmaxf(val.y, 0.f), fmaxf(val.z, 0.f), fmaxf(val.w, 0.f)};
  } else if (MODE == MODE_GD) {
    float4 xo = Xo4[o4];
    Xo4[o4] = {xo.x + val.x, xo.y + val.y, xo.z + val.z, xo.w + val.w};
  } else {  // MODE_G0
    Xo4[o4] = {fmaxf(val.x, 0.f), fmaxf(val.y, 0.f), fmaxf(val.z, 0.f), fmaxf(val.w, 0.f)};
  }
}

// GAT softmax aggregation (2-pass), float4 layout, self loop included.
__global__ __launch_bounds__(256) void k_gat_agg(
    const int* __restrict__ off, const int* __restrict__ idx,
    const float* __restrict__ Hg, const float* __restrict__ al,
    const float* __restrict__ bias, float* __restrict__ Xo,
    float* __restrict__ R, int n) {
  int lane = threadIdx.x & 63;
  int d = blockIdx.x * 4 + (threadIdx.x >> 6);
  if (d >= n) return;
  int rg = lane >> 4, cg = lane & 15;
  int h = cg >> 1;  // head for this lane's 4 channels
  float ald_d = al[d * 16 + 8 + h];
  float eself = lrelu(al[d * 16 + h] + ald_d);
  int beg = off[d], end = off[d + 1];
  const float4* Hg4 = (const float4*)Hg;
  // pass 1: per-head max (incl. self)
  float m = eself;
  for (int base = beg; base < end; base += 64) {
    int cnt = end - base;
    if (cnt > 64) cnt = 64;
    int sidx = (lane < cnt) ? idx[base + lane] : -1;
    int nIter = (cnt + 3) >> 2;
    for (int j = 0; j < nIter; ++j) {
      int s = __shfl(sidx, j * 4 + rg, 64);
      if (s >= 0) m = fmaxf(m, lrelu(al[s * 16 + h] + ald_d));
    }
  }
  m = fmaxf(m, __shfl_xor(m, 16, 64));
  m = fmaxf(m, __shfl_xor(m, 32, 64));
  // pass 2: weighted sum
  float denom = 0.f;
  float4 acc = {0.f, 0.f, 0.f, 0.f};
  for (int base = beg; base < end; base += 64) {
    int cnt = end - base;
    if (cnt > 64) cnt = 64;
    int sidx = (lane < cnt) ? idx[base + lane] : -1;
    int nIter = (cnt + 3) >> 2;
    for (int j = 0; j < nIter; ++j) {
      int s = __shfl(sidx, j * 4 + rg, 64);
      if (s >= 0) {
        float p = __expf(lrelu(al[s * 16 + h] + ald_d) - m);
        denom += p;
        float4 v = Hg4[(size_t)s * 16 + cg];
        acc.x = fmaf(p, v.x, acc.x); acc.y = fmaf(p, v.y, acc.y);
        acc.z = fmaf(p, v.z, acc.z); acc.w = fmaf(p, v.w, acc.w);
      }
    }
  }
#pragma unroll
  for (int mm = 16; mm < 64; mm <<= 1) {
    acc.x += __shfl_xor(acc.x, mm, 64);
    acc.y += __shfl_xor(acc.y, mm, 64);
    acc.z += __shfl_xor(acc.z, mm, 64);
    acc.w += __shfl_xor(acc.w, mm, 64);
    denom += __shfl_xor(denom, mm, 64);
  }
  if (rg != 0) return;
  size_t o4 = (size_t)d * 16 + cg;
  float pself = __expf(eself - m);
  float4 hv = Hg4[o4];
  acc.x = fmaf(pself, hv.x, acc.x); acc.y = fmaf(pself, hv.y, acc.y);
  acc.z = fmaf(pself, hv.z, acc.z); acc.w = fmaf(pself, hv.w, acc.w);
  denom += pself;
  float inv = 1.f / denom;
  float4 b4 = ((const float4*)bias)[cg];
  float4 val = {acc.x * inv + b4.x, acc.y * inv + b4.y,
                acc.z * inv + b4.z, acc.w * inv + b4.w};
  ((float4*)Xo)[o4] = val;
  ((float4*)R)[o4] = val;
}

// ------------------------------- final linear ------------------------------

__global__ __launch_bounds__(256) void k_fc(
    const float* __restrict__ X, const float* __restrict__ W,
    const float* __restrict__ b, float* __restrict__ out, int n) {
  __shared__ float Wl[640];
  __shared__ float bl[10];
  for (int i = threadIdx.x; i < 640; i += 256) Wl[i] = W[i];
  if (threadIdx.x < 10) bl[threadIdx.x] = b[threadIdx.x];
  __syncthreads();
  int r = blockIdx.x * blockDim.x + threadIdx.x;
  if (r >= n) return;
  float acc[10];
#pragma unroll
  for (int c = 0; c < 10; ++c) acc[c] = bl[c];
#pragma unroll
  for (int k = 0; k < 64; ++k) {
    float xv = X[(size_t)r * 64 + k];
#pragma unroll
    for (int c = 0; c < 10; ++c) acc[c] = fmaf(xv, Wl[k * 10 + c], acc[c]);
  }
#pragma unroll
  for (int c = 0; c < 10; ++c) out[(size_t)r * 10 + c] = acc[c];
}

// --------------------------------- launch ----------------------------------

extern "C" void kernel_launch(void* const* d_in, const int* in_sizes, int n_in,
                              void* d_out, int out_size, void* d_ws, size_t ws_size,
                              hipStream_t stream) {
  const float* x_in  = (const float*)d_in[0];
  const int*   ei    = (const int*)d_in[1];
  const float* gatW  = (const float*)d_in[2];
  const float* gatAs = (const float*)d_in[3];
  const float* gatAd = (const float*)d_in[4];
  const float* gatB  = (const float*)d_in[5];
  const float* gcnW  = (const float*)d_in[6];
  const float* gcnB  = (const float*)d_in[7];
  const float* fcW   = (const float*)d_in[8];
  const float* fcB   = (const float*)d_in[9];
  float* out = (float*)d_out;

  const int N = in_sizes[0] / 64;
  const int E = in_sizes[1] / 2;

  char* ws = (char*)d_ws;
  size_t o = 0;
  auto alloc = [&](size_t bytes) -> char* {
    char* p = ws + o;
    o = (o + bytes + 255) & ~(size_t)255;
    return p;
  };
  int* offA   = (int*)alloc((size_t)(N + 1) * 4);
  int* offB   = (int*)alloc((size_t)(N + 1) * 4);
  int* curA   = (int*)alloc((size_t)N * 4);   // doubles as degA
  int* curB   = (int*)alloc((size_t)N * 4);   // doubles as degB
  int* tmp    = (int*)alloc((size_t)N * 4);
  int* bscan  = (int*)alloc(1024 * 4);
  float* dis  = (float*)alloc((size_t)N * 4);
  int* idxA   = (int*)alloc((size_t)E * 4);
  int* idxB   = (int*)alloc((size_t)E * 4);
  float* al   = (float*)alloc((size_t)N * 16 * 4);
  float* X    = (float*)alloc((size_t)N * 64 * 4);
  float* H    = (float*)alloc((size_t)N * 64 * 4);
  float* R    = (float*)alloc((size_t)N * 64 * 4);

  int nbN = (N + 255) / 256;
  int nbE = (E + 255) / 256;
  int nbAgg = (N + 3) / 4;
  int nbG = (N + 255) / 256;

  // ---- CSR build ----
  hipMemsetAsync(curA, 0, (size_t)N * 4, stream);
  hipMemsetAsync(curB, 0, (size_t)N * 4, stream);
  k_count<<<nbE, 256, 0, stream>>>(ei, E, curA, curB);
  k_scan1<<<nbN, 256, 0, stream>>>(curA, tmp, bscan, N);
  k_scan2<<<1, 1024, 0, stream>>>(bscan, nbN);
  k_scan3<<<nbN, 256, 0, stream>>>(tmp, bscan, offA, N);
  k_scan1<<<nbN, 256, 0, stream>>>(curB, tmp, bscan, N);
  k_scan2<<<1, 1024, 0, stream>>>(bscan, nbN);
  k_scan3<<<nbN, 256, 0, stream>>>(tmp, bscan, offB, N);
  k_prep<<<nbN, 256, 0, stream>>>(offA, offB, curA, curB, dis, N);
  k_fill<<<nbE, 256, 0, stream>>>(ei, E, curA, curB, idxA, idxB);

  // ---- random walk: 5 steps, ping-pong ----
  k_agg<MODE_RW><<<nbAgg, 256, 0, stream>>>(offA, idxA, x_in, nullptr, nullptr, nullptr, X, N);
  k_agg<MODE_RW><<<nbAgg, 256, 0, stream>>>(offA, idxA, X, nullptr, nullptr, nullptr, H, N);
  k_agg<MODE_RW><<<nbAgg, 256, 0, stream>>>(offA, idxA, H, nullptr, nullptr, nullptr, X, N);
  k_agg<MODE_RW><<<nbAgg, 256, 0, stream>>>(offA, idxA, X, nullptr, nullptr, nullptr, H, N);
  k_agg<MODE_RW><<<nbAgg, 256, 0, stream>>>(offA, idxA, H, nullptr, nullptr, nullptr, X, N);

  // ---- GAT ----
  k_gat_gemm<<<2048, 256, 0, stream>>>(X, gatW, gatAs, gatAd, H, al, N);
  k_gat_agg<<<nbAgg, 256, 0, stream>>>(offB, idxB, H, al, gatB, X, R, N);

  // ---- residual GCN ----
  for (int i = 0; i < 12; ++i) {
    k_gemm64<true><<<nbG, 256, 0, stream>>>(X, gcnW + i * 4096, dis, H, N);
    if (i == 0)
      k_agg<MODE_G0><<<nbAgg, 256, 0, stream>>>(offB, idxB, H, dis, gcnB + i * 64, nullptr, X, N);
    else
      k_agg<MODE_GR><<<nbAgg, 256, 0, stream>>>(offB, idxB, H, dis, gcnB + i * 64, R, X, N);
    if (i < 11) {
      int j = (i == 0) ? 11 : i - 1;
      k_gemm64<true><<<nbG, 256, 0, stream>>>(X, gcnW + j * 4096, dis, H, N);
      k_agg<MODE_GD><<<nbAgg, 256, 0, stream>>>(offB, idxB, H, dis, gcnB + j * 64, nullptr, X, N);
    }
  }

  // ---- final linear ----
  k_fc<<<nbN, 256, 0, stream>>>(X, fcW, fcB, out, N);
}

// Round 3
// 3049.968 us; speedup vs baseline: 1.3795x; 1.0410x over previous
//
#include <hip/hip_runtime.h>

// ---------------------------------------------------------------------------
// LRA_GNN: random-walk -> 8-head GAT -> 12-layer residual GCN -> FC.
// Round 3: bf16 message tables for all gathers (halves LLC gather traffic),
// 8-rows-per-wave-iter aggregation, lane=row GAT projection GEMM.
// fp32 everywhere else (accumulators, residual chain, attention logits).
// ---------------------------------------------------------------------------

typedef unsigned int u32;

__device__ __forceinline__ float lrelu(float v) { return v > 0.f ? v : 0.2f * v; }
__device__ __forceinline__ float bf_lo(u32 w) { return __uint_as_float(w << 16); }
__device__ __forceinline__ float bf_hi(u32 w) { return __uint_as_float(w & 0xffff0000u); }
// round-to-nearest-even bf16 pack of (a -> lo, b -> hi)
__device__ __forceinline__ u32 pack_bf16(float a, float b) {
  u32 ua = __float_as_uint(a); ua = ua + 0x7fffu + ((ua >> 16) & 1u);
  u32 ub = __float_as_uint(b); ub = ub + 0x7fffu + ((ub >> 16) & 1u);
  return (ua >> 16) | (ub & 0xffff0000u);
}

// ----------------------------- CSR construction ----------------------------

__global__ void k_count(const int* __restrict__ ei, int E,
                        int* __restrict__ degA, int* __restrict__ degB) {
  int e = blockIdx.x * blockDim.x + threadIdx.x;
  if (e < E) {
    atomicAdd(&degA[ei[e]], 1);
    atomicAdd(&degB[ei[E + e]], 1);
  }
}

__global__ void k_scan1(const int* __restrict__ in, int* __restrict__ tmp,
                        int* __restrict__ bsum, int n) {
  __shared__ int s[256];
  int i = blockIdx.x * 256 + threadIdx.x;
  int v = (i < n) ? in[i] : 0;
  s[threadIdx.x] = v;
  __syncthreads();
  for (int d = 1; d < 256; d <<= 1) {
    int t = (threadIdx.x >= d) ? s[threadIdx.x - d] : 0;
    __syncthreads();
    s[threadIdx.x] += t;
    __syncthreads();
  }
  if (i < n) tmp[i] = s[threadIdx.x];
  if (threadIdx.x == 255) bsum[blockIdx.x] = s[255];
}

__global__ void k_scan2(int* __restrict__ bsum, int nb) {
  __shared__ int s[1024];
  int t = threadIdx.x;
  s[t] = (t < nb) ? bsum[t] : 0;
  __syncthreads();
  for (int d = 1; d < 1024; d <<= 1) {
    int v = (t >= d) ? s[t - d] : 0;
    __syncthreads();
    s[t] += v;
    __syncthreads();
  }
  if (t < nb) bsum[t] = s[t];
}

__global__ void k_scan3(const int* __restrict__ tmp, const int* __restrict__ bsum,
                        int* __restrict__ off, int n) {
  int i = blockIdx.x * 256 + threadIdx.x;
  if (i < n) {
    int add = (blockIdx.x > 0) ? bsum[blockIdx.x - 1] : 0;
    off[i + 1] = tmp[i] + add;
    if (i == 0) off[0] = 0;
  }
}

__global__ void k_prep(const int* __restrict__ offA, const int* __restrict__ offB,
                       int* __restrict__ curA, int* __restrict__ curB,
                       float* __restrict__ dis, int n) {
  int i = blockIdx.x * blockDim.x + threadIdx.x;
  if (i < n) {
    curA[i] = offA[i];
    curB[i] = offB[i];
    dis[i] = rsqrtf((float)(offB[i + 1] - offB[i] + 1));
  }
}

__global__ void k_fill(const int* __restrict__ ei, int E,
                       int* __restrict__ curA, int* __restrict__ curB,
                       int* __restrict__ idxA, int* __restrict__ idxB) {
  int e = blockIdx.x * blockDim.x + threadIdx.x;
  if (e < E) {
    int s = ei[e], d = ei[E + e];
    int pa = atomicAdd(&curA[s], 1);
    idxA[pa] = d;
    int pb = atomicAdd(&curB[d], 1);
    idxB[pb] = s;
  }
}

// --------------------------------- GEMMs -----------------------------------

// Hb[row, :] = bf16( dis[row] * (X[row,:] @ W) )   lane = row, acc[64] VGPRs
__global__ __launch_bounds__(256) void k_gemm64(
    const float* __restrict__ X, const float* __restrict__ W,
    const float* __restrict__ dis, u32* __restrict__ Hb, int n) {
  int lane = threadIdx.x & 63;
  int wid = threadIdx.x >> 6;
  int row = (blockIdx.x * 4 + wid) * 64 + lane;
  bool valid = row < n;
  const float4* X4 = (const float4*)X;
  float acc[64];
#pragma unroll
  for (int c = 0; c < 64; ++c) acc[c] = 0.f;
  for (int k4 = 0; k4 < 16; ++k4) {
    float4 xv = valid ? X4[(size_t)row * 16 + k4] : float4{0.f, 0.f, 0.f, 0.f};
    float xs[4] = {xv.x, xv.y, xv.z, xv.w};
#pragma unroll
    for (int kk = 0; kk < 4; ++kk) {
      int k = k4 * 4 + kk;
      float xk = xs[kk];
#pragma unroll
      for (int c = 0; c < 64; ++c)
        acc[c] = fmaf(xk, W[k * 64 + c], acc[c]);
    }
  }
  if (!valid) return;
  float sc = dis[row];
  uint4* H4 = (uint4*)Hb;
#pragma unroll
  for (int q = 0; q < 8; ++q) {
    uint4 o = {pack_bf16(acc[q * 8] * sc, acc[q * 8 + 1] * sc),
               pack_bf16(acc[q * 8 + 2] * sc, acc[q * 8 + 3] * sc),
               pack_bf16(acc[q * 8 + 4] * sc, acc[q * 8 + 5] * sc),
               pack_bf16(acc[q * 8 + 6] * sc, acc[q * 8 + 7] * sc)};
    H4[(size_t)row * 8 + q] = o;
  }
}

// GAT projection from bf16 X: Hgb[row, h*8+dd] = bf16(sum_f x*W[h,f,dd]);
// al[row,0..7] = h.a_src per head, al[row,8..15] = h.a_dst per head.
__global__ __launch_bounds__(256) void k_gat_gemm(
    const u32* __restrict__ Xb, const float* __restrict__ W,
    const float* __restrict__ asrc, const float* __restrict__ adst,
    u32* __restrict__ Hgb, float* __restrict__ al, int n) {
  int lane = threadIdx.x & 63;
  int wid = threadIdx.x >> 6;
  int row = (blockIdx.x * 4 + wid) * 64 + lane;
  bool valid = row < n;
  float acc[64];
#pragma unroll
  for (int c = 0; c < 64; ++c) acc[c] = 0.f;
  const uint4* X4 = (const uint4*)Xb;
  for (int k8 = 0; k8 < 8; ++k8) {
    uint4 xw = valid ? X4[(size_t)row * 8 + k8] : uint4{0u, 0u, 0u, 0u};
    float xs[8] = {bf_lo(xw.x), bf_hi(xw.x), bf_lo(xw.y), bf_hi(xw.y),
                   bf_lo(xw.z), bf_hi(xw.z), bf_lo(xw.w), bf_hi(xw.w)};
#pragma unroll
    for (int kk = 0; kk < 8; ++kk) {
      int k = k8 * 8 + kk;
      float xk = xs[kk];
#pragma unroll
      for (int c = 0; c < 64; ++c)
        acc[c] = fmaf(xk, W[(c >> 3) * 512 + k * 8 + (c & 7)], acc[c]);
    }
  }
  if (!valid) return;
  float alv[16];
#pragma unroll
  for (int h = 0; h < 8; ++h) {
    float s1 = 0.f, s2 = 0.f;
#pragma unroll
    for (int dd = 0; dd < 8; ++dd) {
      s1 = fmaf(acc[h * 8 + dd], asrc[h * 8 + dd], s1);
      s2 = fmaf(acc[h * 8 + dd], adst[h * 8 + dd], s2);
    }
    alv[h] = s1;
    alv[8 + h] = s2;
  }
  float4* al4 = (float4*)al;
#pragma unroll
  for (int q = 0; q < 4; ++q)
    al4[(size_t)row * 4 + q] = {alv[q * 4], alv[q * 4 + 1], alv[q * 4 + 2], alv[q * 4 + 3]};
  uint4* H4 = (uint4*)Hgb;
#pragma unroll
  for (int q = 0; q < 8; ++q) {
    uint4 o = {pack_bf16(acc[q * 8], acc[q * 8 + 1]),
               pack_bf16(acc[q * 8 + 2], acc[q * 8 + 3]),
               pack_bf16(acc[q * 8 + 4], acc[q * 8 + 5]),
               pack_bf16(acc[q * 8 + 6], acc[q * 8 + 7])};
    H4[(size_t)row * 8 + q] = o;
  }
}

// ------------------------------ aggregations -------------------------------

enum { MODE_RW1 = 0, MODE_RW = 1, MODE_G0 = 2, MODE_GR = 3, MODE_GD = 4 };

// One wave per destination node. lane = (rg 0..7, cg 0..7); 8 neighbor rows
// per wave-iter, 16 B (8 bf16 ch) per lane; fp32 accumulate.
template <int MODE>
__global__ __launch_bounds__(256) void k_agg(
    const int* __restrict__ off, const int* __restrict__ idx,
    const float* __restrict__ Hf, const u32* __restrict__ Hb,
    const float* __restrict__ dis, const float* __restrict__ bias,
    float* __restrict__ R, float* __restrict__ Xf, u32* __restrict__ Xb,
    int n) {
  int lane = threadIdx.x & 63;
  int d = blockIdx.x * 4 + (threadIdx.x >> 6);
  if (d >= n) return;
  int rg = lane >> 3, cg = lane & 7;
  int beg = off[d], end = off[d + 1];
  float acc[8];
#pragma unroll
  for (int i = 0; i < 8; ++i) acc[i] = 0.f;
  for (int base = beg; base < end; base += 64) {
    int cnt = end - base;
    if (cnt > 64) cnt = 64;
    int sidx = (lane < cnt) ? idx[base + lane] : -1;
    int nIter = (cnt + 7) >> 3;
    for (int j = 0; j < nIter; ++j) {
      int s = __shfl(sidx, j * 8 + rg, 64);
      if (s >= 0) {
        if (MODE == MODE_RW1) {
          const float4* p = (const float4*)Hf + ((size_t)s * 16 + cg * 2);
          float4 x = p[0], y = p[1];
          acc[0] += x.x; acc[1] += x.y; acc[2] += x.z; acc[3] += x.w;
          acc[4] += y.x; acc[5] += y.y; acc[6] += y.z; acc[7] += y.w;
        } else {
          uint4 w = ((const uint4*)Hb)[(size_t)s * 8 + cg];
          acc[0] += bf_lo(w.x); acc[1] += bf_hi(w.x);
          acc[2] += bf_lo(w.y); acc[3] += bf_hi(w.y);
          acc[4] += bf_lo(w.z); acc[5] += bf_hi(w.z);
          acc[6] += bf_lo(w.w); acc[7] += bf_hi(w.w);
        }
      }
    }
  }
#pragma unroll
  for (int m = 8; m < 64; m <<= 1)
#pragma unroll
    for (int i = 0; i < 8; ++i) acc[i] += __shfl_xor(acc[i], m, 64);
  if (rg != 0) return;
  // lanes 0..7, cg == lane
  if (MODE == MODE_RW1 || MODE == MODE_RW) {
    uint4 o = {pack_bf16(acc[0], acc[1]), pack_bf16(acc[2], acc[3]),
               pack_bf16(acc[4], acc[5]), pack_bf16(acc[6], acc[7])};
    ((uint4*)Xb)[(size_t)d * 8 + cg] = o;
    return;
  }
  float ddv = dis[d];
  uint4 hw = ((const uint4*)Hb)[(size_t)d * 8 + cg];
  float hs[8] = {bf_lo(hw.x), bf_hi(hw.x), bf_lo(hw.y), bf_hi(hw.y),
                 bf_lo(hw.z), bf_hi(hw.z), bf_lo(hw.w), bf_hi(hw.w)};
  float4 b0 = ((const float4*)bias)[cg * 2];
  float4 b1 = ((const float4*)bias)[cg * 2 + 1];
  float bv[8] = {b0.x, b0.y, b0.z, b0.w, b1.x, b1.y, b1.z, b1.w};
  float v[8];
#pragma unroll
  for (int i = 0; i < 8; ++i) v[i] = ddv * (acc[i] + hs[i]) + bv[i];
  float4* X4 = (float4*)Xf;
  size_t o0 = (size_t)d * 16 + cg * 2;
  if (MODE == MODE_GR) {
    float4* R4 = (float4*)R;
    float4 r0 = R4[o0], r1 = R4[o0 + 1];
    v[0] += r0.x; v[1] += r0.y; v[2] += r0.z; v[3] += r0.w;
    v[4] += r1.x; v[5] += r1.y; v[6] += r1.z; v[7] += r1.w;
    R4[o0] = {v[0], v[1], v[2], v[3]};
    R4[o0 + 1] = {v[4], v[5], v[6], v[7]};
    X4[o0] = {fmaxf(v[0], 0.f), fmaxf(v[1], 0.f), fmaxf(v[2], 0.f), fmaxf(v[3], 0.f)};
    X4[o0 + 1] = {fmaxf(v[4], 0.f), fmaxf(v[5], 0.f), fmaxf(v[6], 0.f), fmaxf(v[7], 0.f)};
  } else if (MODE == MODE_GD) {
    float4 x0 = X4[o0], x1 = X4[o0 + 1];
    X4[o0] = {x0.x + v[0], x0.y + v[1], x0.z + v[2], x0.w + v[3]};
    X4[o0 + 1] = {x1.x + v[4], x1.y + v[5], x1.z + v[6], x1.w + v[7]};
  } else {  // MODE_G0
    X4[o0] = {fmaxf(v[0], 0.f), fmaxf(v[1], 0.f), fmaxf(v[2], 0.f), fmaxf(v[3], 0.f)};
    X4[o0 + 1] = {fmaxf(v[4], 0.f), fmaxf(v[5], 0.f), fmaxf(v[6], 0.f), fmaxf(v[7], 0.f)};
  }
}

// GAT softmax aggregation (2-pass); head = cg; bf16 Hg, fp32 logits al.
__global__ __launch_bounds__(256) void k_gat_agg(
    const int* __restrict__ off, const int* __restrict__ idx,
    const u32* __restrict__ Hgb, const float* __restrict__ al,
    const float* __restrict__ bias, float* __restrict__ X,
    float* __restrict__ R, int n) {
  int lane = threadIdx.x & 63;
  int d = blockIdx.x * 4 + (threadIdx.x >> 6);
  if (d >= n) return;
  int rg = lane >> 3, cg = lane & 7;
  float ald = al[(size_t)d * 16 + 8 + cg];
  float eself = lrelu(al[(size_t)d * 16 + cg] + ald);
  int beg = off[d], end = off[d + 1];
  // pass 1: per-head max (incl. self)
  float m = eself;
  for (int base = beg; base < end; base += 64) {
    int cnt = end - base;
    if (cnt > 64) cnt = 64;
    int sidx = (lane < cnt) ? idx[base + lane] : -1;
    int nIter = (cnt + 7) >> 3;
    for (int j = 0; j < nIter; ++j) {
      int s = __shfl(sidx, j * 8 + rg, 64);
      if (s >= 0) m = fmaxf(m, lrelu(al[(size_t)s * 16 + cg] + ald));
    }
  }
#pragma unroll
  for (int mm = 8; mm < 64; mm <<= 1) m = fmaxf(m, __shfl_xor(m, mm, 64));
  // pass 2: weighted sum
  float denom = 0.f;
  float acc[8];
#pragma unroll
  for (int i = 0; i < 8; ++i) acc[i] = 0.f;
  for (int base = beg; base < end; base += 64) {
    int cnt = end - base;
    if (cnt > 64) cnt = 64;
    int sidx = (lane < cnt) ? idx[base + lane] : -1;
    int nIter = (cnt + 7) >> 3;
    for (int j = 0; j < nIter; ++j) {
      int s = __shfl(sidx, j * 8 + rg, 64);
      if (s >= 0) {
        float p = __expf(lrelu(al[(size_t)s * 16 + cg] + ald) - m);
        denom += p;
        uint4 w = ((const uint4*)Hgb)[(size_t)s * 8 + cg];
        acc[0] = fmaf(p, bf_lo(w.x), acc[0]); acc[1] = fmaf(p, bf_hi(w.x), acc[1]);
        acc[2] = fmaf(p, bf_lo(w.y), acc[2]); acc[3] = fmaf(p, bf_hi(w.y), acc[3]);
        acc[4] = fmaf(p, bf_lo(w.z), acc[4]); acc[5] = fmaf(p, bf_hi(w.z), acc[5]);
        acc[6] = fmaf(p, bf_lo(w.w), acc[6]); acc[7] = fmaf(p, bf_hi(w.w), acc[7]);
      }
    }
  }
#pragma unroll
  for (int mm = 8; mm < 64; mm <<= 1) {
#pragma unroll
    for (int i = 0; i < 8; ++i) acc[i] += __shfl_xor(acc[i], mm, 64);
    denom += __shfl_xor(denom, mm, 64);
  }
  if (rg != 0) return;
  float pself = __expf(eself - m);
  uint4 hw = ((const uint4*)Hgb)[(size_t)d * 8 + cg];
  float hs[8] = {bf_lo(hw.x), bf_hi(hw.x), bf_lo(hw.y), bf_hi(hw.y),
                 bf_lo(hw.z), bf_hi(hw.z), bf_lo(hw.w), bf_hi(hw.w)};
#pragma unroll
  for (int i = 0; i < 8; ++i) acc[i] = fmaf(pself, hs[i], acc[i]);
  denom += pself;
  float inv = 1.f / denom;
  float4 b0 = ((const float4*)bias)[cg * 2];
  float4 b1 = ((const float4*)bias)[cg * 2 + 1];
  float bv[8] = {b0.x, b0.y, b0.z, b0.w, b1.x, b1.y, b1.z, b1.w};
  float v[8];
#pragma unroll
  for (int i = 0; i < 8; ++i) v[i] = acc[i] * inv + bv[i];
  size_t o0 = (size_t)d * 16 + cg * 2;
  ((float4*)X)[o0] = {v[0], v[1], v[2], v[3]};
  ((float4*)X)[o0 + 1] = {v[4], v[5], v[6], v[7]};
  ((float4*)R)[o0] = {v[0], v[1], v[2], v[3]};
  ((float4*)R)[o0 + 1] = {v[4], v[5], v[6], v[7]};
}

// ------------------------------- final linear ------------------------------

__global__ __launch_bounds__(256) void k_fc(
    const float* __restrict__ X, const float* __restrict__ W,
    const float* __restrict__ b, float* __restrict__ out, int n) {
  __shared__ float Wl[640];
  __shared__ float bl[10];
  for (int i = threadIdx.x; i < 640; i += 256) Wl[i] = W[i];
  if (threadIdx.x < 10) bl[threadIdx.x] = b[threadIdx.x];
  __syncthreads();
  int r = blockIdx.x * blockDim.x + threadIdx.x;
  if (r >= n) return;
  float acc[10];
#pragma unroll
  for (int c = 0; c < 10; ++c) acc[c] = bl[c];
#pragma unroll
  for (int k = 0; k < 64; ++k) {
    float xv = X[(size_t)r * 64 + k];
#pragma unroll
    for (int c = 0; c < 10; ++c) acc[c] = fmaf(xv, Wl[k * 10 + c], acc[c]);
  }
#pragma unroll
  for (int c = 0; c < 10; ++c) out[(size_t)r * 10 + c] = acc[c];
}

// --------------------------------- launch ----------------------------------

extern "C" void kernel_launch(void* const* d_in, const int* in_sizes, int n_in,
                              void* d_out, int out_size, void* d_ws, size_t ws_size,
                              hipStream_t stream) {
  const float* x_in  = (const float*)d_in[0];
  const int*   ei    = (const int*)d_in[1];
  const float* gatW  = (const float*)d_in[2];
  const float* gatAs = (const float*)d_in[3];
  const float* gatAd = (const float*)d_in[4];
  const float* gatB  = (const float*)d_in[5];
  const float* gcnW  = (const float*)d_in[6];
  const float* gcnB  = (const float*)d_in[7];
  const float* fcW   = (const float*)d_in[8];
  const float* fcB   = (const float*)d_in[9];
  float* out = (float*)d_out;

  const int N = in_sizes[0] / 64;
  const int E = in_sizes[1] / 2;

  char* ws = (char*)d_ws;
  size_t o = 0;
  auto alloc = [&](size_t bytes) -> char* {
    char* p = ws + o;
    o = (o + bytes + 255) & ~(size_t)255;
    return p;
  };
  int* offA   = (int*)alloc((size_t)(N + 1) * 4);
  int* offB   = (int*)alloc((size_t)(N + 1) * 4);
  int* curA   = (int*)alloc((size_t)N * 4);
  int* curB   = (int*)alloc((size_t)N * 4);
  int* tmp    = (int*)alloc((size_t)N * 4);
  int* bscan  = (int*)alloc(1024 * 4);
  float* dis  = (float*)alloc((size_t)N * 4);
  int* idxA   = (int*)alloc((size_t)E * 4);
  int* idxB   = (int*)alloc((size_t)E * 4);
  float* al   = (float*)alloc((size_t)N * 16 * 4);
  u32* B0     = (u32*)alloc((size_t)N * 32 * 4);   // bf16 table [N][64]
  u32* B1     = (u32*)alloc((size_t)N * 32 * 4);   // bf16 table [N][64]
  float* X    = (float*)alloc((size_t)N * 64 * 4);
  float* R    = (float*)alloc((size_t)N * 64 * 4);

  int nbN = (N + 255) / 256;
  int nbE = (E + 255) / 256;
  int nbAgg = (N + 3) / 4;
  int nbG = (N + 255) / 256;

  // ---- CSR build ----
  hipMemsetAsync(curA, 0, (size_t)N * 4, stream);
  hipMemsetAsync(curB, 0, (size_t)N * 4, stream);
  k_count<<<nbE, 256, 0, stream>>>(ei, E, curA, curB);
  k_scan1<<<nbN, 256, 0, stream>>>(curA, tmp, bscan, N);
  k_scan2<<<1, 1024, 0, stream>>>(bscan, nbN);
  k_scan3<<<nbN, 256, 0, stream>>>(tmp, bscan, offA, N);
  k_scan1<<<nbN, 256, 0, stream>>>(curB, tmp, bscan, N);
  k_scan2<<<1, 1024, 0, stream>>>(bscan, nbN);
  k_scan3<<<nbN, 256, 0, stream>>>(tmp, bscan, offB, N);
  k_prep<<<nbN, 256, 0, stream>>>(offA, offB, curA, curB, dis, N);
  k_fill<<<nbE, 256, 0, stream>>>(ei, E, curA, curB, idxA, idxB);

  // ---- random walk: 5 steps (fp32 in -> bf16 ping-pong) ----
  k_agg<MODE_RW1><<<nbAgg, 256, 0, stream>>>(offA, idxA, x_in, nullptr, nullptr, nullptr, nullptr, nullptr, B0, N);
  k_agg<MODE_RW><<<nbAgg, 256, 0, stream>>>(offA, idxA, nullptr, B0, nullptr, nullptr, nullptr, nullptr, B1, N);
  k_agg<MODE_RW><<<nbAgg, 256, 0, stream>>>(offA, idxA, nullptr, B1, nullptr, nullptr, nullptr, nullptr, B0, N);
  k_agg<MODE_RW><<<nbAgg, 256, 0, stream>>>(offA, idxA, nullptr, B0, nullptr, nullptr, nullptr, nullptr, B1, N);
  k_agg<MODE_RW><<<nbAgg, 256, 0, stream>>>(offA, idxA, nullptr, B1, nullptr, nullptr, nullptr, nullptr, B0, N);

  // ---- GAT ----
  k_gat_gemm<<<nbG, 256, 0, stream>>>(B0, gatW, gatAs, gatAd, B1, al, N);
  k_gat_agg<<<nbAgg, 256, 0, stream>>>(offB, idxB, B1, al, gatB, X, R, N);

  // ---- residual GCN ----
  for (int i = 0; i < 12; ++i) {
    k_gemm64<<<nbG, 256, 0, stream>>>(X, gcnW + i * 4096, dis, B0, N);
    if (i == 0)
      k_agg<MODE_G0><<<nbAgg, 256, 0, stream>>>(offB, idxB, nullptr, B0, dis, gcnB + i * 64, nullptr, X, nullptr, N);
    else
      k_agg<MODE_GR><<<nbAgg, 256, 0, stream>>>(offB, idxB, nullptr, B0, dis, gcnB + i * 64, R, X, nullptr, N);
    if (i < 11) {
      int j = (i == 0) ? 11 : i - 1;
      k_gemm64<<<nbG, 256, 0, stream>>>(X, gcnW + j * 4096, dis, B0, N);
      k_agg<MODE_GD><<<nbAgg, 256, 0, stream>>>(offB, idxB, nullptr, B0, dis, gcnB + j * 64, nullptr, X, nullptr, N);
    }
  }

  // ---- final linear ----
  k_fc<<<nbN, 256, 0, stream>>>(X, fcW, fcB, out, N);
}

// Round 4
// 2696.713 us; speedup vs baseline: 1.5602x; 1.1310x over previous
//
#include <hip/hip_runtime.h>

// ---------------------------------------------------------------------------
// LRA_GNN: random-walk -> 8-head GAT -> 12-layer residual GCN -> FC.
// Round 4: CSR build via bucketed counting sort (node>>7 buckets) — replaces
// atomic scatter k_count/k_fill whose cross-XCD line bouncing cost ~600us.
// Aggregation (bf16 tables) and GEMMs unchanged from round 3.
// ---------------------------------------------------------------------------

typedef unsigned int u32;

#define BSH 7              // bucket shift: 128 nodes per bucket
#define RNGB 128           // nodes per bucket
#define GEB 256            // edge-pass blocks

__device__ __forceinline__ float lrelu(float v) { return v > 0.f ? v : 0.2f * v; }
__device__ __forceinline__ float bf_lo(u32 w) { return __uint_as_float(w << 16); }
__device__ __forceinline__ float bf_hi(u32 w) { return __uint_as_float(w & 0xffff0000u); }
__device__ __forceinline__ u32 pack_bf16(float a, float b) {
  u32 ua = __float_as_uint(a); ua = ua + 0x7fffu + ((ua >> 16) & 1u);
  u32 ub = __float_as_uint(b); ub = ub + 0x7fffu + ((ub >> 16) & 1u);
  return (ua >> 16) | (ub & 0xffff0000u);
}

// --------------------- CSR build via bucketed counting sort ----------------

// Pass 1: per-(block,bucket) histograms for both orderings.
__global__ __launch_bounds__(256) void k_hist(
    const int* __restrict__ ei, int E, int NB, int chunk,
    int* __restrict__ gHistA, int* __restrict__ gHistB) {
  __shared__ int hA[1024], hB[1024];
  for (int i = threadIdx.x; i < NB; i += 256) { hA[i] = 0; hB[i] = 0; }
  __syncthreads();
  int e0 = blockIdx.x * chunk;
  int e1 = min(E, e0 + chunk);
  for (int e = e0 + threadIdx.x; e < e1; e += 256) {
    int s = ei[e], d = ei[E + e];
    atomicAdd(&hA[s >> BSH], 1);
    atomicAdd(&hB[d >> BSH], 1);
  }
  __syncthreads();
  for (int i = threadIdx.x; i < NB; i += 256) {
    gHistA[blockIdx.x * NB + i] = hA[i];
    gHistB[blockIdx.x * NB + i] = hB[i];
  }
}

// Pass 2: per-bucket scan across blocks -> in-place exclusive starts + totals.
__global__ __launch_bounds__(256) void k_colscan(
    int* __restrict__ gHist, int* __restrict__ tot, int NB) {
  __shared__ int s[GEB];
  int b = blockIdx.x;
  int t = threadIdx.x;
  int v = gHist[t * NB + b];
  s[t] = v;
  __syncthreads();
  for (int d = 1; d < GEB; d <<= 1) {
    int u = (t >= d) ? s[t - d] : 0;
    __syncthreads();
    s[t] += u;
    __syncthreads();
  }
  gHist[t * NB + b] = s[t] - v;   // exclusive within bucket
  if (t == GEB - 1) tot[b] = s[t];
}

// Pass 3: exclusive scan of bucket totals -> bucket bases (A and B).
__global__ __launch_bounds__(1024) void k_bscan(
    const int* __restrict__ totA, const int* __restrict__ totB,
    int* __restrict__ baseA, int* __restrict__ baseB,
    int* __restrict__ offA, int* __restrict__ offB, int NB, int N, int E) {
  __shared__ int sa[1024], sb[1024];
  int t = threadIdx.x;
  int va = (t < NB) ? totA[t] : 0;
  int vb = (t < NB) ? totB[t] : 0;
  sa[t] = va; sb[t] = vb;
  __syncthreads();
  for (int d = 1; d < 1024; d <<= 1) {
    int ua = (t >= d) ? sa[t - d] : 0;
    int ub = (t >= d) ? sb[t - d] : 0;
    __syncthreads();
    sa[t] += ua; sb[t] += ub;
    __syncthreads();
  }
  if (t < NB) { baseA[t] = sa[t] - va; baseB[t] = sb[t] - vb; }
  if (t == 0) { offA[N] = E; offB[N] = E; }
}

// Pass 4: scatter edges into bucket-major pair arrays (private sub-ranges).
__global__ __launch_bounds__(256) void k_scatter(
    const int* __restrict__ ei, int E, int NB, int chunk,
    const int* __restrict__ gHistA, const int* __restrict__ gHistB,
    const int* __restrict__ baseA, const int* __restrict__ baseB,
    int2* __restrict__ pairsA, int2* __restrict__ pairsB) {
  __shared__ int cA[1024], cB[1024];
  int g = blockIdx.x;
  for (int i = threadIdx.x; i < NB; i += 256) {
    cA[i] = baseA[i] + gHistA[g * NB + i];
    cB[i] = baseB[i] + gHistB[g * NB + i];
  }
  __syncthreads();
  int e0 = g * chunk;
  int e1 = min(E, e0 + chunk);
  for (int e = e0 + threadIdx.x; e < e1; e += 256) {
    int s = ei[e], d = ei[E + e];
    int pa = atomicAdd(&cA[s >> BSH], 1);
    pairsA[pa] = {s, d};
    int pb = atomicAdd(&cB[d >> BSH], 1);
    pairsB[pb] = {s, d};
  }
}

// Pass 5: per-bucket finalize: node degrees -> off[], (dis[]), idx fill.
// KEY=0: key=s (CSR_A, value d).  KEY=1: key=d (CSR_B, value s), writes dis.
template <int KEY>
__global__ __launch_bounds__(256) void k_bucket(
    const int2* __restrict__ pairs, const int* __restrict__ base,
    const int* __restrict__ tot, int* __restrict__ off,
    int* __restrict__ idx, float* __restrict__ dis, int N) {
  __shared__ int cnt[RNGB], pfx[RNGB];
  int b = blockIdx.x;
  int node0 = b << BSH;
  int rng = min(RNGB, N - node0);
  int bstart = base[b], bcount = tot[b];
  for (int i = threadIdx.x; i < rng; i += 256) cnt[i] = 0;
  __syncthreads();
  for (int i = threadIdx.x; i < bcount; i += 256) {
    int2 p = pairs[bstart + i];
    int loc = (KEY == 0 ? p.x : p.y) - node0;
    atomicAdd(&cnt[loc], 1);
  }
  __syncthreads();
  if (threadIdx.x == 0) {
    int run = 0;
    for (int i = 0; i < rng; ++i) { pfx[i] = run; run += cnt[i]; }
  }
  __syncthreads();
  for (int i = threadIdx.x; i < rng; i += 256) {
    off[node0 + i] = bstart + pfx[i];
    if (KEY == 1) dis[node0 + i] = rsqrtf((float)(cnt[i] + 1));
  }
  __syncthreads();
  // reuse pfx as running cursors
  for (int i = threadIdx.x; i < bcount; i += 256) {
    int2 p = pairs[bstart + i];
    int loc = (KEY == 0 ? p.x : p.y) - node0;
    int pos = bstart + atomicAdd(&pfx[loc], 1);
    idx[pos] = (KEY == 0 ? p.y : p.x);
  }
}

// --------------------------------- GEMMs -----------------------------------

__global__ __launch_bounds__(256) void k_gemm64(
    const float* __restrict__ X, const float* __restrict__ W,
    const float* __restrict__ dis, u32* __restrict__ Hb, int n) {
  int lane = threadIdx.x & 63;
  int wid = threadIdx.x >> 6;
  int row = (blockIdx.x * 4 + wid) * 64 + lane;
  bool valid = row < n;
  const float4* X4 = (const float4*)X;
  float acc[64];
#pragma unroll
  for (int c = 0; c < 64; ++c) acc[c] = 0.f;
  for (int k4 = 0; k4 < 16; ++k4) {
    float4 xv = valid ? X4[(size_t)row * 16 + k4] : float4{0.f, 0.f, 0.f, 0.f};
    float xs[4] = {xv.x, xv.y, xv.z, xv.w};
#pragma unroll
    for (int kk = 0; kk < 4; ++kk) {
      int k = k4 * 4 + kk;
      float xk = xs[kk];
#pragma unroll
      for (int c = 0; c < 64; ++c)
        acc[c] = fmaf(xk, W[k * 64 + c], acc[c]);
    }
  }
  if (!valid) return;
  float sc = dis[row];
  uint4* H4 = (uint4*)Hb;
#pragma unroll
  for (int q = 0; q < 8; ++q) {
    uint4 o = {pack_bf16(acc[q * 8] * sc, acc[q * 8 + 1] * sc),
               pack_bf16(acc[q * 8 + 2] * sc, acc[q * 8 + 3] * sc),
               pack_bf16(acc[q * 8 + 4] * sc, acc[q * 8 + 5] * sc),
               pack_bf16(acc[q * 8 + 6] * sc, acc[q * 8 + 7] * sc)};
    H4[(size_t)row * 8 + q] = o;
  }
}

__global__ __launch_bounds__(256) void k_gat_gemm(
    const u32* __restrict__ Xb, const float* __restrict__ W,
    const float* __restrict__ asrc, const float* __restrict__ adst,
    u32* __restrict__ Hgb, float* __restrict__ al, int n) {
  int lane = threadIdx.x & 63;
  int wid = threadIdx.x >> 6;
  int row = (blockIdx.x * 4 + wid) * 64 + lane;
  bool valid = row < n;
  float acc[64];
#pragma unroll
  for (int c = 0; c < 64; ++c) acc[c] = 0.f;
  const uint4* X4 = (const uint4*)Xb;
  for (int k8 = 0; k8 < 8; ++k8) {
    uint4 xw = valid ? X4[(size_t)row * 8 + k8] : uint4{0u, 0u, 0u, 0u};
    float xs[8] = {bf_lo(xw.x), bf_hi(xw.x), bf_lo(xw.y), bf_hi(xw.y),
                   bf_lo(xw.z), bf_hi(xw.z), bf_lo(xw.w), bf_hi(xw.w)};
#pragma unroll
    for (int kk = 0; kk < 8; ++kk) {
      int k = k8 * 8 + kk;
      float xk = xs[kk];
#pragma unroll
      for (int c = 0; c < 64; ++c)
        acc[c] = fmaf(xk, W[(c >> 3) * 512 + k * 8 + (c & 7)], acc[c]);
    }
  }
  if (!valid) return;
  float alv[16];
#pragma unroll
  for (int h = 0; h < 8; ++h) {
    float s1 = 0.f, s2 = 0.f;
#pragma unroll
    for (int dd = 0; dd < 8; ++dd) {
      s1 = fmaf(acc[h * 8 + dd], asrc[h * 8 + dd], s1);
      s2 = fmaf(acc[h * 8 + dd], adst[h * 8 + dd], s2);
    }
    alv[h] = s1;
    alv[8 + h] = s2;
  }
  float4* al4 = (float4*)al;
#pragma unroll
  for (int q = 0; q < 4; ++q)
    al4[(size_t)row * 4 + q] = {alv[q * 4], alv[q * 4 + 1], alv[q * 4 + 2], alv[q * 4 + 3]};
  uint4* H4 = (uint4*)Hgb;
#pragma unroll
  for (int q = 0; q < 8; ++q) {
    uint4 o = {pack_bf16(acc[q * 8], acc[q * 8 + 1]),
               pack_bf16(acc[q * 8 + 2], acc[q * 8 + 3]),
               pack_bf16(acc[q * 8 + 4], acc[q * 8 + 5]),
               pack_bf16(acc[q * 8 + 6], acc[q * 8 + 7])};
    H4[(size_t)row * 8 + q] = o;
  }
}

// ------------------------------ aggregations -------------------------------

enum { MODE_RW1 = 0, MODE_RW = 1, MODE_G0 = 2, MODE_GR = 3, MODE_GD = 4 };

template <int MODE>
__global__ __launch_bounds__(256) void k_agg(
    const int* __restrict__ off, const int* __restrict__ idx,
    const float* __restrict__ Hf, const u32* __restrict__ Hb,
    const float* __restrict__ dis, const float* __restrict__ bias,
    float* __restrict__ R, float* __restrict__ Xf, u32* __restrict__ Xb,
    int n) {
  int lane = threadIdx.x & 63;
  int d = blockIdx.x * 4 + (threadIdx.x >> 6);
  if (d >= n) return;
  int rg = lane >> 3, cg = lane & 7;
  int beg = off[d], end = off[d + 1];
  float acc[8];
#pragma unroll
  for (int i = 0; i < 8; ++i) acc[i] = 0.f;
  for (int base = beg; base < end; base += 64) {
    int cnt = end - base;
    if (cnt > 64) cnt = 64;
    int sidx = (lane < cnt) ? idx[base + lane] : -1;
    int nIter = (cnt + 7) >> 3;
    for (int j = 0; j < nIter; ++j) {
      int s = __shfl(sidx, j * 8 + rg, 64);
      if (s >= 0) {
        if (MODE == MODE_RW1) {
          const float4* p = (const float4*)Hf + ((size_t)s * 16 + cg * 2);
          float4 x = p[0], y = p[1];
          acc[0] += x.x; acc[1] += x.y; acc[2] += x.z; acc[3] += x.w;
          acc[4] += y.x; acc[5] += y.y; acc[6] += y.z; acc[7] += y.w;
        } else {
          uint4 w = ((const uint4*)Hb)[(size_t)s * 8 + cg];
          acc[0] += bf_lo(w.x); acc[1] += bf_hi(w.x);
          acc[2] += bf_lo(w.y); acc[3] += bf_hi(w.y);
          acc[4] += bf_lo(w.z); acc[5] += bf_hi(w.z);
          acc[6] += bf_lo(w.w); acc[7] += bf_hi(w.w);
        }
      }
    }
  }
#pragma unroll
  for (int m = 8; m < 64; m <<= 1)
#pragma unroll
    for (int i = 0; i < 8; ++i) acc[i] += __shfl_xor(acc[i], m, 64);
  if (rg != 0) return;
  if (MODE == MODE_RW1 || MODE == MODE_RW) {
    uint4 o = {pack_bf16(acc[0], acc[1]), pack_bf16(acc[2], acc[3]),
               pack_bf16(acc[4], acc[5]), pack_bf16(acc[6], acc[7])};
    ((uint4*)Xb)[(size_t)d * 8 + cg] = o;
    return;
  }
  float ddv = dis[d];
  uint4 hw = ((const uint4*)Hb)[(size_t)d * 8 + cg];
  float hs[8] = {bf_lo(hw.x), bf_hi(hw.x), bf_lo(hw.y), bf_hi(hw.y),
                 bf_lo(hw.z), bf_hi(hw.z), bf_lo(hw.w), bf_hi(hw.w)};
  float4 b0 = ((const float4*)bias)[cg * 2];
  float4 b1 = ((const float4*)bias)[cg * 2 + 1];
  float bv[8] = {b0.x, b0.y, b0.z, b0.w, b1.x, b1.y, b1.z, b1.w};
  float v[8];
#pragma unroll
  for (int i = 0; i < 8; ++i) v[i] = ddv * (acc[i] + hs[i]) + bv[i];
  float4* X4 = (float4*)Xf;
  size_t o0 = (size_t)d * 16 + cg * 2;
  if (MODE == MODE_GR) {
    float4* R4 = (float4*)R;
    float4 r0 = R4[o0], r1 = R4[o0 + 1];
    v[0] += r0.x; v[1] += r0.y; v[2] += r0.z; v[3] += r0.w;
    v[4] += r1.x; v[5] += r1.y; v[6] += r1.z; v[7] += r1.w;
    R4[o0] = {v[0], v[1], v[2], v[3]};
    R4[o0 + 1] = {v[4], v[5], v[6], v[7]};
    X4[o0] = {fmaxf(v[0], 0.f), fmaxf(v[1], 0.f), fmaxf(v[2], 0.f), fmaxf(v[3], 0.f)};
    X4[o0 + 1] = {fmaxf(v[4], 0.f), fmaxf(v[5], 0.f), fmaxf(v[6], 0.f), fmaxf(v[7], 0.f)};
  } else if (MODE == MODE_GD) {
    float4 x0 = X4[o0], x1 = X4[o0 + 1];
    X4[o0] = {x0.x + v[0], x0.y + v[1], x0.z + v[2], x0.w + v[3]};
    X4[o0 + 1] = {x1.x + v[4], x1.y + v[5], x1.z + v[6], x1.w + v[7]};
  } else {  // MODE_G0
    X4[o0] = {fmaxf(v[0], 0.f), fmaxf(v[1], 0.f), fmaxf(v[2], 0.f), fmaxf(v[3], 0.f)};
    X4[o0 + 1] = {fmaxf(v[4], 0.f), fmaxf(v[5], 0.f), fmaxf(v[6], 0.f), fmaxf(v[7], 0.f)};
  }
}

__global__ __launch_bounds__(256) void k_gat_agg(
    const int* __restrict__ off, const int* __restrict__ idx,
    const u32* __restrict__ Hgb, const float* __restrict__ al,
    const float* __restrict__ bias, float* __restrict__ X,
    float* __restrict__ R, int n) {
  int lane = threadIdx.x & 63;
  int d = blockIdx.x * 4 + (threadIdx.x >> 6);
  if (d >= n) return;
  int rg = lane >> 3, cg = lane & 7;
  float ald = al[(size_t)d * 16 + 8 + cg];
  float eself = lrelu(al[(size_t)d * 16 + cg] + ald);
  int beg = off[d], end = off[d + 1];
  float m = eself;
  for (int base = beg; base < end; base += 64) {
    int cnt = end - base;
    if (cnt > 64) cnt = 64;
    int sidx = (lane < cnt) ? idx[base + lane] : -1;
    int nIter = (cnt + 7) >> 3;
    for (int j = 0; j < nIter; ++j) {
      int s = __shfl(sidx, j * 8 + rg, 64);
      if (s >= 0) m = fmaxf(m, lrelu(al[(size_t)s * 16 + cg] + ald));
    }
  }
#pragma unroll
  for (int mm = 8; mm < 64; mm <<= 1) m = fmaxf(m, __shfl_xor(m, mm, 64));
  float denom = 0.f;
  float acc[8];
#pragma unroll
  for (int i = 0; i < 8; ++i) acc[i] = 0.f;
  for (int base = beg; base < end; base += 64) {
    int cnt = end - base;
    if (cnt > 64) cnt = 64;
    int sidx = (lane < cnt) ? idx[base + lane] : -1;
    int nIter = (cnt + 7) >> 3;
    for (int j = 0; j < nIter; ++j) {
      int s = __shfl(sidx, j * 8 + rg, 64);
      if (s >= 0) {
        float p = __expf(lrelu(al[(size_t)s * 16 + cg] + ald) - m);
        denom += p;
        uint4 w = ((const uint4*)Hgb)[(size_t)s * 8 + cg];
        acc[0] = fmaf(p, bf_lo(w.x), acc[0]); acc[1] = fmaf(p, bf_hi(w.x), acc[1]);
        acc[2] = fmaf(p, bf_lo(w.y), acc[2]); acc[3] = fmaf(p, bf_hi(w.y), acc[3]);
        acc[4] = fmaf(p, bf_lo(w.z), acc[4]); acc[5] = fmaf(p, bf_hi(w.z), acc[5]);
        acc[6] = fmaf(p, bf_lo(w.w), acc[6]); acc[7] = fmaf(p, bf_hi(w.w), acc[7]);
      }
    }
  }
#pragma unroll
  for (int mm = 8; mm < 64; mm <<= 1) {
#pragma unroll
    for (int i = 0; i < 8; ++i) acc[i] += __shfl_xor(acc[i], mm, 64);
    denom += __shfl_xor(denom, mm, 64);
  }
  if (rg != 0) return;
  float pself = __expf(eself - m);
  uint4 hw = ((const uint4*)Hgb)[(size_t)d * 8 + cg];
  float hs[8] = {bf_lo(hw.x), bf_hi(hw.x), bf_lo(hw.y), bf_hi(hw.y),
                 bf_lo(hw.z), bf_hi(hw.z), bf_lo(hw.w), bf_hi(hw.w)};
#pragma unroll
  for (int i = 0; i < 8; ++i) acc[i] = fmaf(pself, hs[i], acc[i]);
  denom += pself;
  float inv = 1.f / denom;
  float4 b0 = ((const float4*)bias)[cg * 2];
  float4 b1 = ((const float4*)bias)[cg * 2 + 1];
  float bv[8] = {b0.x, b0.y, b0.z, b0.w, b1.x, b1.y, b1.z, b1.w};
  float v[8];
#pragma unroll
  for (int i = 0; i < 8; ++i) v[i] = acc[i] * inv + bv[i];
  size_t o0 = (size_t)d * 16 + cg * 2;
  ((float4*)X)[o0] = {v[0], v[1], v[2], v[3]};
  ((float4*)X)[o0 + 1] = {v[4], v[5], v[6], v[7]};
  ((float4*)R)[o0] = {v[0], v[1], v[2], v[3]};
  ((float4*)R)[o0 + 1] = {v[4], v[5], v[6], v[7]};
}

// ------------------------------- final linear ------------------------------

__global__ __launch_bounds__(256) void k_fc(
    const float* __restrict__ X, const float* __restrict__ W,
    const float* __restrict__ b, float* __restrict__ out, int n) {
  __shared__ float Wl[640];
  __shared__ float bl[10];
  for (int i = threadIdx.x; i < 640; i += 256) Wl[i] = W[i];
  if (threadIdx.x < 10) bl[threadIdx.x] = b[threadIdx.x];
  __syncthreads();
  int r = blockIdx.x * blockDim.x + threadIdx.x;
  if (r >= n) return;
  float acc[10];
#pragma unroll
  for (int c = 0; c < 10; ++c) acc[c] = bl[c];
#pragma unroll
  for (int k = 0; k < 64; ++k) {
    float xv = X[(size_t)r * 64 + k];
#pragma unroll
    for (int c = 0; c < 10; ++c) acc[c] = fmaf(xv, Wl[k * 10 + c], acc[c]);
  }
#pragma unroll
  for (int c = 0; c < 10; ++c) out[(size_t)r * 10 + c] = acc[c];
}

// --------------------------------- launch ----------------------------------

extern "C" void kernel_launch(void* const* d_in, const int* in_sizes, int n_in,
                              void* d_out, int out_size, void* d_ws, size_t ws_size,
                              hipStream_t stream) {
  const float* x_in  = (const float*)d_in[0];
  const int*   ei    = (const int*)d_in[1];
  const float* gatW  = (const float*)d_in[2];
  const float* gatAs = (const float*)d_in[3];
  const float* gatAd = (const float*)d_in[4];
  const float* gatB  = (const float*)d_in[5];
  const float* gcnW  = (const float*)d_in[6];
  const float* gcnB  = (const float*)d_in[7];
  const float* fcW   = (const float*)d_in[8];
  const float* fcB   = (const float*)d_in[9];
  float* out = (float*)d_out;

  const int N = in_sizes[0] / 64;
  const int E = in_sizes[1] / 2;
  const int NB = (N + RNGB - 1) >> BSH;       // buckets (<=1024 for N<=128K)
  const int chunk = (E + GEB - 1) / GEB;

  char* ws = (char*)d_ws;
  size_t o = 0;
  auto alloc = [&](size_t bytes) -> char* {
    char* p = ws + o;
    o = (o + bytes + 255) & ~(size_t)255;
    return p;
  };
  int* offA    = (int*)alloc((size_t)(N + 1) * 4);
  int* offB    = (int*)alloc((size_t)(N + 1) * 4);
  float* dis   = (float*)alloc((size_t)N * 4);
  int* idxA    = (int*)alloc((size_t)E * 4);
  int* idxB    = (int*)alloc((size_t)E * 4);
  int2* pairsA = (int2*)alloc((size_t)E * 8);
  int2* pairsB = (int2*)alloc((size_t)E * 8);
  int* gHistA  = (int*)alloc((size_t)GEB * NB * 4);
  int* gHistB  = (int*)alloc((size_t)GEB * NB * 4);
  int* totA    = (int*)alloc((size_t)NB * 4);
  int* totB    = (int*)alloc((size_t)NB * 4);
  int* baseA   = (int*)alloc((size_t)NB * 4);
  int* baseB   = (int*)alloc((size_t)NB * 4);
  float* al    = (float*)alloc((size_t)N * 16 * 4);
  u32* B0      = (u32*)alloc((size_t)N * 32 * 4);   // bf16 table [N][64]
  u32* B1      = (u32*)alloc((size_t)N * 32 * 4);   // bf16 table [N][64]
  float* X     = (float*)alloc((size_t)N * 64 * 4);
  float* R     = (float*)alloc((size_t)N * 64 * 4);

  int nbN = (N + 255) / 256;
  int nbAgg = (N + 3) / 4;
  int nbG = (N + 255) / 256;

  // ---- CSR build: bucketed counting sort ----
  k_hist<<<GEB, 256, 0, stream>>>(ei, E, NB, chunk, gHistA, gHistB);
  k_colscan<<<NB, GEB, 0, stream>>>(gHistA, totA, NB);
  k_colscan<<<NB, GEB, 0, stream>>>(gHistB, totB, NB);
  k_bscan<<<1, 1024, 0, stream>>>(totA, totB, baseA, baseB, offA, offB, NB, N, E);
  k_scatter<<<GEB, 256, 0, stream>>>(ei, E, NB, chunk, gHistA, gHistB,
                                     baseA, baseB, pairsA, pairsB);
  k_bucket<0><<<NB, 256, 0, stream>>>(pairsA, baseA, totA, offA, idxA, nullptr, N);
  k_bucket<1><<<NB, 256, 0, stream>>>(pairsB, baseB, totB, offB, idxB, dis, N);

  // ---- random walk: 5 steps (fp32 in -> bf16 ping-pong) ----
  k_agg<MODE_RW1><<<nbAgg, 256, 0, stream>>>(offA, idxA, x_in, nullptr, nullptr, nullptr, nullptr, nullptr, B0, N);
  k_agg<MODE_RW><<<nbAgg, 256, 0, stream>>>(offA, idxA, nullptr, B0, nullptr, nullptr, nullptr, nullptr, B1, N);
  k_agg<MODE_RW><<<nbAgg, 256, 0, stream>>>(offA, idxA, nullptr, B1, nullptr, nullptr, nullptr, nullptr, B0, N);
  k_agg<MODE_RW><<<nbAgg, 256, 0, stream>>>(offA, idxA, nullptr, B0, nullptr, nullptr, nullptr, nullptr, B1, N);
  k_agg<MODE_RW><<<nbAgg, 256, 0, stream>>>(offA, idxA, nullptr, B1, nullptr, nullptr, nullptr, nullptr, B0, N);

  // ---- GAT ----
  k_gat_gemm<<<nbG, 256, 0, stream>>>(B0, gatW, gatAs, gatAd, B1, al, N);
  k_gat_agg<<<nbAgg, 256, 0, stream>>>(offB, idxB, B1, al, gatB, X, R, N);

  // ---- residual GCN ----
  for (int i = 0; i < 12; ++i) {
    k_gemm64<<<nbG, 256, 0, stream>>>(X, gcnW + i * 4096, dis, B0, N);
    if (i == 0)
      k_agg<MODE_G0><<<nbAgg, 256, 0, stream>>>(offB, idxB, nullptr, B0, dis, gcnB + i * 64, nullptr, X, nullptr, N);
    else
      k_agg<MODE_GR><<<nbAgg, 256, 0, stream>>>(offB, idxB, nullptr, B0, dis, gcnB + i * 64, R, X, nullptr, N);
    if (i < 11) {
      int j = (i == 0) ? 11 : i - 1;
      k_gemm64<<<nbG, 256, 0, stream>>>(X, gcnW + j * 4096, dis, B0, N);
      k_agg<MODE_GD><<<nbAgg, 256, 0, stream>>>(offB, idxB, nullptr, B0, dis, gcnB + j * 64, nullptr, X, nullptr, N);
    }
  }

  // ---- final linear ----
  k_fc<<<nbN, 256, 0, stream>>>(X, fcW, fcB, out, N);
}